// Round 8
// baseline (607.888 us; speedup 1.0000x reference)
//
#include <hip/hip_runtime.h>
#include <hip/hip_bf16.h>
#include <stdint.h>

// ---------------- static problem sizes ----------------
#define BB    32
#define NPER  1024
#define NTOT  32768
#define DD    128
#define HH    4
#define HD    32
#define LL    3
#define DFF   2048
#define INDIM 64
#define QKSCALE 0.17677669529663687f

typedef unsigned short u16;
typedef short bf16x8 __attribute__((ext_vector_type(8)));   // 8 bf16 (4 VGPRs)
typedef float f32x4 __attribute__((ext_vector_type(4)));

// address-space casts for global_load_lds (direct global->LDS DMA)
#define AS_GLOBAL(p) ((const __attribute__((address_space(1))) void*)(p))
#define AS_LDS(p)    ((__attribute__((address_space(3))) void*)(p))

__device__ __forceinline__ float bf2f(u16 v){
  unsigned u = ((unsigned)v) << 16; float f; __builtin_memcpy(&f, &u, 4); return f;
}
__device__ __forceinline__ u16 f2bf(float f){
  unsigned u; __builtin_memcpy(&u, &f, 4);
  unsigned lsb = (u >> 16) & 1u;
  u += 0x7fffu + lsb;              // round-to-nearest-even
  return (u16)(u >> 16);
}

// ---------------- workspace layout (bytes) ----------------
constexpr size_t OFF_FLAG   = 0;
constexpr size_t OFF_STARTS = 256;
constexpr size_t OFF_BIN    = 1024;
constexpr size_t OFF_BQKV   = OFF_BIN   + 128*4;
constexpr size_t OFF_BO     = OFF_BQKV  + 1152*4;
constexpr size_t OFF_B1     = OFF_BO    + 384*4;
constexpr size_t OFF_B2     = OFF_B1    + 6144*4;
constexpr size_t OFF_LN1G   = OFF_B2    + 384*4;
constexpr size_t OFF_LN1B   = OFF_LN1G  + 384*4;
constexpr size_t OFF_LN2G   = OFF_LN1B  + 384*4;
constexpr size_t OFF_LN2B   = OFF_LN2G  + 384*4;
constexpr size_t OFF_XB     = 40960;
constexpr size_t OFF_WINB   = OFF_XB    + (size_t)2097152*2;
constexpr size_t OFF_WQKVB  = OFF_WINB  + (size_t)8192*2;
constexpr size_t OFF_WOB    = OFF_WQKVB + (size_t)147456*2;
constexpr size_t OFF_W1B    = OFF_WOB   + (size_t)49152*2;
constexpr size_t OFF_W2B    = OFF_W1B   + (size_t)786432*2;
constexpr size_t OFF_CUR    = OFF_W2B   + (size_t)786432*2;
constexpr size_t OFF_TMP    = OFF_CUR   + (size_t)4194304*4;
constexpr size_t OFF_CURB   = OFF_TMP   + (size_t)4194304*4;
constexpr size_t OFF_QKVB   = OFF_CURB  + (size_t)4194304*2;
constexpr size_t OFF_ATTNOB = OFF_QKVB  + (size_t)12582912*2;
constexpr size_t OFF_ACTB   = OFF_ATTNOB+ (size_t)4194304*2;     // (unused now)
constexpr size_t OFF_MASK   = OFF_ACTB  + (size_t)16777216*2;
constexpr size_t OFF_VT     = OFF_MASK  + (size_t)NTOT*4;
constexpr size_t OFF_RED    = OFF_VT    + (size_t)4096*1024*2;
constexpr size_t OFF_CNT    = OFF_RED   + (size_t)32*8*128*4;

// ---------------- dtype detection ----------------
__device__ __forceinline__ int plaus(unsigned bits){
  if ((bits << 1) == 0u) return 1;
  unsigned e = (bits >> 23) & 0xFFu;
  return (e >= 100u && e <= 140u) ? 1 : 0;
}
__global__ void detect_kernel(const unsigned* __restrict__ x, int* __restrict__ flag){
  __shared__ int red[256];
  int t = threadIdx.x, c = 0;
  for (int i = t; i < 2048; i += 256){
    unsigned w = x[i];
    c += (plaus(w << 16) & plaus(w & 0xFFFF0000u));
  }
  red[t] = c; __syncthreads();
  for (int s = 128; s > 0; s >>= 1){ if (t < s) red[t] += red[t+s]; __syncthreads(); }
  if (t == 0) *flag = (red[0] >= 1229) ? 1 : 0;
}

__global__ void starts_kernel(const int* __restrict__ batch, int* __restrict__ starts){
  int b = threadIdx.x;
  if (b < BB){
    int lo = 0, hi = NTOT;
    while (lo < hi){ int mid = (lo + hi) >> 1; if (batch[mid] < b) lo = mid + 1; else hi = mid; }
    starts[b] = lo;
  }
}

// ---------------- fused conversion of all 15 float tensors (1 launch) ----------------
struct ConvSeg { const void* src; void* dst; int n; int tobf; };
struct ConvArgs { ConvSeg s[15]; };

__global__ __launch_bounds__(256) void convall_kernel(ConvArgs a, const int* __restrict__ flag){
  const int isb = *flag;
  const int blk = blockIdx.x;
  int seg = -1, base = 0, lb = 0;
  #pragma unroll
  for (int i = 0; i < 15; ++i){
    int nb = (a.s[i].n + 1023) >> 10;
    if (seg < 0){
      if (blk < base + nb){ seg = i; lb = blk - base; }
      base += nb;
    }
  }
  const ConvSeg sg = a.s[seg];
  const int idx = lb*1024 + threadIdx.x*4;
  if (idx >= sg.n) return;
  if (sg.tobf){
    u16* dst = (u16*)sg.dst + idx;
    if (isb){
      *(uint2*)dst = *(const uint2*)((const u16*)sg.src + idx);
    } else {
      const float* s4 = (const float*)sg.src + idx;
      dst[0] = f2bf(s4[0]); dst[1] = f2bf(s4[1]);
      dst[2] = f2bf(s4[2]); dst[3] = f2bf(s4[3]);
    }
  } else {
    float* dst = (float*)sg.dst + idx;
    if (isb){
      const u16* s4 = (const u16*)sg.src + idx;
      dst[0] = bf2f(s4[0]); dst[1] = bf2f(s4[1]);
      dst[2] = bf2f(s4[2]); dst[3] = bf2f(s4[3]);
    } else {
      *(float4*)dst = *(const float4*)((const float*)sg.src + idx);
    }
  }
}

// ---------------- legacy small GEMM (input projection only) ----------------
__global__ __launch_bounds__(256) void gemm_bf16(
    const u16* __restrict__ A, int lda,
    const u16* __restrict__ W, int ldw,
    const float* __restrict__ bias,
    float* __restrict__ Cf, u16* __restrict__ Cb,
    int N, int K, int flags)
{
  __shared__ __align__(16) u16 At[64][32];
  __shared__ __align__(16) u16 Wt[64][32];
  const int t = threadIdx.x;
  const int m0 = blockIdx.x * 64, n0 = blockIdx.y * 64;
  const int wave = t >> 6, lane = t & 63;
  const int quad = lane >> 4, l16 = lane & 15;
  const int lr = t >> 2, lc = (t & 3) * 8;

  f32x4 acc[4];
  #pragma unroll
  for (int i = 0; i < 4; ++i){ acc[i][0]=0.f; acc[i][1]=0.f; acc[i][2]=0.f; acc[i][3]=0.f; }

  const u16* Arow = A + (size_t)(m0 + lr) * lda + lc;
  const u16* Wrow = W + (size_t)(n0 + lr) * ldw + lc;

  for (int k0 = 0; k0 < K; k0 += 32){
    uint4 av = *(const uint4*)(Arow + k0);
    uint4 wv = *(const uint4*)(Wrow + k0);
    __syncthreads();
    *(uint4*)&At[lr][lc] = av;
    *(uint4*)&Wt[lr][lc] = wv;
    __syncthreads();
    bf16x8 af = *(const bf16x8*)&At[wave*16 + l16][quad*8];
    #pragma unroll
    for (int nt = 0; nt < 4; ++nt){
      bf16x8 wf = *(const bf16x8*)&Wt[nt*16 + l16][quad*8];
      acc[nt] = __builtin_amdgcn_mfma_f32_16x16x32_bf16(af, wf, acc[nt], 0, 0, 0);
    }
  }
  const int row = m0 + wave*16 + quad*4;
  #pragma unroll
  for (int nt = 0; nt < 4; ++nt){
    const int col = n0 + nt*16 + l16;
    const float bv = bias ? bias[col] : 0.f;
    #pragma unroll
    for (int r = 0; r < 4; ++r){
      size_t idx = (size_t)(row + r) * N + col;
      float v = acc[nt][r] + bv;
      if (flags & 1) v = fmaxf(v, 0.f);
      if (Cf) Cf[idx] = v;
      if (Cb) Cb[idx] = f2bf(v);
    }
  }
}

// ---------------- scatter projected nodes into padded layout + mask ----------------
__global__ __launch_bounds__(128) void scatter_kernel(
    const float* __restrict__ hlin, const int* __restrict__ batch,
    const int* __restrict__ starts, float* __restrict__ cur,
    u16* __restrict__ curb, float* __restrict__ mask)
{
  int i = blockIdx.x, t = threadIdx.x;
  int g = batch[i];
  int p = i - starts[g];
  float v = hlin[(size_t)i*DD + t];
  float s = v;
  #pragma unroll
  for (int off = 32; off; off >>= 1) s += __shfl_xor(s, off);
  __shared__ float sh[2];
  if ((t & 63) == 0) sh[t >> 6] = s;
  __syncthreads();
  float rowsum = sh[0] + sh[1];
  if ((unsigned)p < (unsigned)NPER && (unsigned)g < (unsigned)BB){
    size_t j = (size_t)g*NPER + p;
    cur[j*DD + t]  = v;
    curb[j*DD + t] = f2bf(v);
    if (t == 0) mask[j] = (rowsum != 0.f) ? 1.f : 0.f;
  }
}

// ---------------- MFMA flash attention v2 ----------------
__global__ __launch_bounds__(256) void fattn_kernel(
    const u16* __restrict__ qkvb,   // [NTOT][384]
    const u16* __restrict__ vt,     // [B*H*HD][NPER]
    u16* __restrict__ attnob)       // [NTOT][128]
{
  __shared__ __align__(16) u16 Klds[2][2048];      // [c(4)][r(64)][8]
  __shared__ __align__(16) u16 Vl[2][2048];        // [cv(8)][d(32)][8]
  __shared__ __align__(16) u16 Pl[4][16*72];       // per-wave P [q][s], pitch 72

  const int t = threadIdx.x;
  const int wave = t >> 6, lane = t & 63;
  const int quad = lane >> 4, l16 = lane & 15;
  const int q0 = blockIdx.x * 64;
  const int h = blockIdx.y, b = blockIdx.z;
  const size_t qkvbase = (size_t)b * NPER * 384;
  const u16* Kg = qkvb + qkvbase + 128 + h*HD;
  const u16* Vg = vt + (size_t)((b*HH + h)*HD) * NPER;

  bf16x8 qf;
  {
    const u16* qp = qkvb + qkvbase + (size_t)(q0 + wave*16 + l16)*384 + h*HD + quad*8;
    uint4 qv = *(const uint4*)qp;
    u16 raw[8]; __builtin_memcpy(raw, &qv, 16);
    #pragma unroll
    for (int j = 0; j < 8; ++j) qf[j] = (short)f2bf(bf2f(raw[j]) * QKSCALE);
  }

  const int vcv = wave*2 + (lane >> 5), vd = lane & 31;
  auto stage = [&](int buf, int kt){
    __builtin_amdgcn_global_load_lds(
        AS_GLOBAL(Kg + (size_t)(kt*64 + lane)*384 + wave*8),
        AS_LDS(&Klds[buf][wave*64*8]), 16, 0, 0);
    __builtin_amdgcn_global_load_lds(
        AS_GLOBAL(Vg + (size_t)vd*NPER + kt*64 + vcv*8),
        AS_LDS(&Vl[buf][wave*64*8]), 16, 0, 0);
  };

  float lsum = 0.f;
  f32x4 o0 = {0.f,0.f,0.f,0.f}, o1 = {0.f,0.f,0.f,0.f};
  u16* Pw = &Pl[wave][0];

  stage(0, 0);
  asm volatile("s_waitcnt vmcnt(0)" ::: "memory");
  __syncthreads();

  for (int kt = 0; kt < 16; ++kt){
    const int buf = kt & 1;
    if (kt + 1 < 16) stage(buf ^ 1, kt + 1);

    f32x4 sfr[4];
    #pragma unroll
    for (int nt = 0; nt < 4; ++nt){
      bf16x8 kf = *(const bf16x8*)&Klds[buf][(quad*64 + nt*16 + l16)*8];
      f32x4 z = {0.f,0.f,0.f,0.f};
      sfr[nt] = __builtin_amdgcn_mfma_f32_16x16x32_bf16(kf, qf, z, 0, 0, 0);
    }

    float ps = 0.f;
    #pragma unroll
    for (int nt = 0; nt < 4; ++nt){
      float e0 = __expf(sfr[nt][0]), e1 = __expf(sfr[nt][1]);
      float e2 = __expf(sfr[nt][2]), e3 = __expf(sfr[nt][3]);
      ps += (e0 + e1) + (e2 + e3);
      uint2 w;
      w.x = (unsigned)f2bf(e0) | ((unsigned)f2bf(e1) << 16);
      w.y = (unsigned)f2bf(e2) | ((unsigned)f2bf(e3) << 16);
      *(uint2*)&Pw[l16*72 + nt*16 + quad*4] = w;
    }
    ps += __shfl_xor(ps, 16);
    ps += __shfl_xor(ps, 32);
    lsum += ps;
    asm volatile("s_waitcnt lgkmcnt(0)" ::: "memory");

    #pragma unroll
    for (int kk = 0; kk < 2; ++kk){
      bf16x8 pf = *(const bf16x8*)&Pw[l16*72 + kk*32 + quad*8];
      bf16x8 v0 = *(const bf16x8*)&Vl[buf][((kk*4 + quad)*32 + l16)*8];
      bf16x8 v1 = *(const bf16x8*)&Vl[buf][((kk*4 + quad)*32 + 16 + l16)*8];
      o0 = __builtin_amdgcn_mfma_f32_16x16x32_bf16(pf, v0, o0, 0, 0, 0);
      o1 = __builtin_amdgcn_mfma_f32_16x16x32_bf16(pf, v1, o1, 0, 0, 0);
    }

    if (kt + 1 < 16){
      asm volatile("s_waitcnt vmcnt(0)" ::: "memory");
      __syncthreads();
    }
  }

  #pragma unroll
  for (int r = 0; r < 4; ++r){
    float inv = 1.f / __shfl(lsum, quad*4 + r);
    int row = q0 + wave*16 + quad*4 + r;
    size_t base = (size_t)(b*NPER + row)*DD + h*HD;
    attnob[base + l16]      = f2bf(o0[r] * inv);
    attnob[base + 16 + l16] = f2bf(o1[r] * inv);
  }
}

// ---------------- LN epilogue (wave owns 16 rows): out = LN(resid + O + bias) ----------------
__device__ __forceinline__ void epilogue_ln64(
    const f32x4 O[8], int m0, int wave, int quad, int l16,
    const float* __restrict__ bias, const float* __restrict__ g,
    const float* __restrict__ beta, float* __restrict__ cur,
    u16* __restrict__ curb)
{
  #pragma unroll
  for (int rr = 0; rr < 4; ++rr){
    int row = m0 + wave*16 + quad*4 + rr;
    float vs[8], sum = 0.f;
    #pragma unroll
    for (int nt = 0; nt < 8; ++nt){
      int col = nt*16 + l16;
      float v = O[nt][rr] + bias[col] + cur[(size_t)row*DD + col];
      vs[nt] = v; sum += v;
    }
    sum += __shfl_xor(sum, 1); sum += __shfl_xor(sum, 2);
    sum += __shfl_xor(sum, 4); sum += __shfl_xor(sum, 8);
    float mean = sum * (1.f/DD);
    float sq = 0.f;
    #pragma unroll
    for (int nt = 0; nt < 8; ++nt){ float d = vs[nt] - mean; sq += d*d; }
    sq += __shfl_xor(sq, 1); sq += __shfl_xor(sq, 2);
    sq += __shfl_xor(sq, 4); sq += __shfl_xor(sq, 8);
    float rs = rsqrtf(sq * (1.f/DD) + 1e-5f);
    #pragma unroll
    for (int nt = 0; nt < 8; ++nt){
      int col = nt*16 + l16;
      float o = (vs[nt] - mean)*rs*g[col] + beta[col];
      cur[(size_t)row*DD + col]  = o;
      curb[(size_t)row*DD + col] = f2bf(o);
    }
  }
}

// ---------------- 64-row-block GEMM, W (128x128 slice) in LDS, A-frags in regs ----------------
__global__ __launch_bounds__(256) void wgemm_kernel(
    const u16* __restrict__ A,        // [M][128] bf16
    const u16* __restrict__ Wbase,    // [gridDim.y*128][128] bf16
    const float* __restrict__ biasb,  // [gridDim.y*128]
    int mode,
    u16* __restrict__ outb, int opitch,
    u16* __restrict__ vtout,
    float* __restrict__ cur, u16* __restrict__ curb,
    const float* __restrict__ g, const float* __restrict__ beta)
{
  __shared__ __align__(16) u16 Wl[16384];          // 128x128, XOR-swizzled chunks
  const int t = threadIdx.x, wave = t >> 6, lane = t & 63;
  const int quad = lane >> 4, l16 = lane & 15;
  const int m0 = blockIdx.x * 64, nb = blockIdx.y;
  const u16* Wsl = Wbase + (size_t)nb * 16384;
  const float* bias = biasb + nb * 128;

  #pragma unroll
  for (int j = 0; j < 8; ++j){
    int s = t + 256*j;
    int r = s >> 4, cx = (s & 15) ^ (r & 15);
    *(uint4*)&Wl[s*8] = *(const uint4*)(Wsl + (size_t)r*128 + cx*8);
  }
  bf16x8 af[4];
  #pragma unroll
  for (int kk = 0; kk < 4; ++kk)
    af[kk] = *(const bf16x8*)(A + (size_t)(m0 + wave*16 + l16)*128 + kk*32 + quad*8);
  __syncthreads();

  f32x4 O[8];
  #pragma unroll
  for (int nt = 0; nt < 8; ++nt){ O[nt][0]=0.f; O[nt][1]=0.f; O[nt][2]=0.f; O[nt][3]=0.f; }

  #pragma unroll
  for (int nt = 0; nt < 8; ++nt){
    int row = nt*16 + l16;
    bf16x8 wf[4];
    #pragma unroll
    for (int kk = 0; kk < 4; ++kk)
      wf[kk] = *(const bf16x8*)&Wl[(row*16 + ((kk*4 + quad) ^ l16))*8];
    #pragma unroll
    for (int kk = 0; kk < 4; ++kk)
      O[nt] = __builtin_amdgcn_mfma_f32_16x16x32_bf16(af[kk], wf[kk], O[nt], 0, 0, 0);
  }

  if (mode == 0){
    if (nb == 2 && vtout){
      int rowb = m0 + wave*16 + quad*4;
      int bg = rowb >> 10, s = rowb & 1023;
      #pragma unroll
      for (int nt = 0; nt < 8; ++nt){
        int col = nt*16 + l16;
        int hh = col >> 5, d = col & 31;
        float v0 = O[nt][0] + bias[col], v1 = O[nt][1] + bias[col];
        float v2 = O[nt][2] + bias[col], v3 = O[nt][3] + bias[col];
        uint2 w;
        w.x = (unsigned)f2bf(v0) | ((unsigned)f2bf(v1) << 16);
        w.y = (unsigned)f2bf(v2) | ((unsigned)f2bf(v3) << 16);
        *(uint2*)(vtout + (size_t)((bg*HH + hh)*HD + d)*NPER + s) = w;
      }
    } else {
      #pragma unroll
      for (int rr = 0; rr < 4; ++rr){
        int row = m0 + wave*16 + quad*4 + rr;
        #pragma unroll
        for (int nt = 0; nt < 8; ++nt){
          int col = nt*16 + l16;
          outb[(size_t)row*opitch + nb*128 + col] = f2bf(O[nt][rr] + bias[col]);
        }
      }
    }
  } else {
    epilogue_ln64(O, m0, wave, quad, l16, bias, g, beta, cur, curb);
  }
}

// ---------------- fused FFN v3: 128-row blocks, wave owns 32 rows ----------------
// grid 256 (1 block/CU). Halves per-CU LDS W-fragment read duplication vs R7
// (8 waves/CU x 34 reads -> 4 waves x 36 reads for 2x MFMA each).
// Phase1 operand-swapped (mfma(wf, af)) so P is written as packed b64.
// P: per-wave [act32][dff64] pitch 64, XOR chunk swizzle keyed on row&7.
// __launch_bounds__(256,1): full VGPR budget; live set ~180 (O 64 + af 32 + frags).
__global__ __launch_bounds__(256, 1) void ffn_kernel(
    const u16* __restrict__ Ag,       // CURB [M][128]
    const u16* __restrict__ W1g,      // [2048][128]
    const u16* __restrict__ W2g,      // [128][2048]
    const float* __restrict__ b1,
    const float* __restrict__ b2,
    const float* __restrict__ g, const float* __restrict__ beta,
    float* __restrict__ cur, u16* __restrict__ curb)
{
  __shared__ __align__(16) u16 W1l[2][8192];       // 64x128 chunk, swizzled, x2 buf
  __shared__ __align__(16) u16 W2l[2][8192];       // 128x64 chunk, swizzled, x2 buf
  __shared__ __align__(16) u16 Pl[4][2048];        // per-wave P[32][64], swizzled

  const int t = threadIdx.x, wave = t >> 6, lane = t & 63;
  const int quad = lane >> 4, l16 = lane & 15;
  const int e = l16 & 7;
  const int m0 = blockIdx.x * 128;
  u16* Pw = &Pl[wave][0];

  auto stage = [&](int buf, int dffc){
    #pragma unroll
    for (int i = 0; i < 4; ++i){
      const int s0 = wave*256 + i*64;
      const int s  = s0 + lane;
      { int r = s >> 4, cx = (s & 15) ^ (r & 15);
        __builtin_amdgcn_global_load_lds(
            AS_GLOBAL(W1g + (size_t)(dffc + r)*128 + cx*8),
            AS_LDS(&W1l[buf][s0*8]), 16, 0, 0); }
      { int r = s >> 3, cx = (s & 7) ^ (r & 7);
        __builtin_amdgcn_global_load_lds(
            AS_GLOBAL(W2g + (size_t)r*DFF + dffc + cx*8),
            AS_LDS(&W2l[buf][s0*8]), 16, 0, 0); }
    }
  };

  // A-frags in regs (wave owns 32 rows: mt=0,1)
  bf16x8 af[2][4];
  #pragma unroll
  for (int mt = 0; mt < 2; ++mt)
    #pragma unroll
    for (int kk = 0; kk < 4; ++kk)
      af[mt][kk] = *(const bf16x8*)(Ag + (size_t)(m0 + wave*32 + mt*16 + l16)*128 + kk*32 + quad*8);

  f32x4 O[2][8];
  #pragma unroll
  for (int mt = 0; mt < 2; ++mt)
    #pragma unroll
    for (int nt = 0; nt < 8; ++nt){ O[mt][nt][0]=0.f; O[mt][nt][1]=0.f; O[mt][nt][2]=0.f; O[mt][nt][3]=0.f; }

  stage(0, 0);
  asm volatile("s_waitcnt vmcnt(0)" ::: "memory");
  __syncthreads();

  for (int c = 0; c < 32; ++c){
    const int buf = c & 1;
    if (c + 1 < 32) stage(buf ^ 1, (c + 1)*64);

    // phase 1 (operand-swapped): C[dff=quad*4+r][act=l16] per (nt,mt) tile
    #pragma unroll
    for (int nt = 0; nt < 4; ++nt){
      int row = nt*16 + l16;                       // dff-local row for wf load
      bf16x8 wf[4];
      #pragma unroll
      for (int kk = 0; kk < 4; ++kk)
        wf[kk] = *(const bf16x8*)&W1l[buf][(row*16 + ((kk*4 + quad) ^ l16))*8];
      f32x4 b1v = *(const f32x4*)&b1[c*64 + nt*16 + quad*4];
      #pragma unroll
      for (int mt = 0; mt < 2; ++mt){
        f32x4 s = {0.f,0.f,0.f,0.f};
        #pragma unroll
        for (int kk = 0; kk < 4; ++kk)
          s = __builtin_amdgcn_mfma_f32_16x16x32_bf16(wf[kk], af[mt][kk], s, 0, 0, 0);
        float v0 = fmaxf(s[0] + b1v[0], 0.f), v1 = fmaxf(s[1] + b1v[1], 0.f);
        float v2 = fmaxf(s[2] + b1v[2], 0.f), v3 = fmaxf(s[3] + b1v[3], 0.f);
        uint2 w;
        w.x = (unsigned)f2bf(v0) | ((unsigned)f2bf(v1) << 16);
        w.y = (unsigned)f2bf(v2) | ((unsigned)f2bf(v3) << 16);
        // P[act=mt*16+l16][dff=nt*16+quad*4 .. +3], chunk swizzle ^ (row&7)=e
        *(uint2*)&Pw[(mt*16 + l16)*64 + (((nt*2 + (quad >> 1)) ^ e) << 3) + ((quad & 1) << 2)] = w;
      }
    }
    asm volatile("s_waitcnt lgkmcnt(0)" ::: "memory");

    // phase 2: O += P @ W2c^T
    bf16x8 pf[2][2];
    #pragma unroll
    for (int mt = 0; mt < 2; ++mt)
      #pragma unroll
      for (int kk = 0; kk < 2; ++kk)
        pf[mt][kk] = *(const bf16x8*)&Pw[(mt*16 + l16)*64 + (((kk*4 + quad) ^ e) << 3)];
    #pragma unroll
    for (int nt = 0; nt < 8; ++nt){
      int row = nt*16 + l16;                       // output-col row of W2
      bf16x8 wf[2];
      #pragma unroll
      for (int kk = 0; kk < 2; ++kk)
        wf[kk] = *(const bf16x8*)&W2l[buf][(row*8 + ((kk*4 + quad) ^ e))*8];
      #pragma unroll
      for (int mt = 0; mt < 2; ++mt)
        #pragma unroll
        for (int kk = 0; kk < 2; ++kk)
          O[mt][nt] = __builtin_amdgcn_mfma_f32_16x16x32_bf16(pf[mt][kk], wf[kk], O[mt][nt], 0, 0, 0);
    }

    if (c + 1 < 32){
      asm volatile("s_waitcnt vmcnt(0)" ::: "memory");
      __syncthreads();
    }
  }

  // epilogue: residual + LN2 over both 16-row tiles
  #pragma unroll
  for (int mt = 0; mt < 2; ++mt){
    #pragma unroll
    for (int rr = 0; rr < 4; ++rr){
      int row = m0 + wave*32 + mt*16 + quad*4 + rr;
      float vs[8], sum = 0.f;
      #pragma unroll
      for (int nt = 0; nt < 8; ++nt){
        int col = nt*16 + l16;
        float v = O[mt][nt][rr] + b2[col] + cur[(size_t)row*DD + col];
        vs[nt] = v; sum += v;
      }
      sum += __shfl_xor(sum, 1); sum += __shfl_xor(sum, 2);
      sum += __shfl_xor(sum, 4); sum += __shfl_xor(sum, 8);
      float mean = sum * (1.f/DD);
      float sq = 0.f;
      #pragma unroll
      for (int nt = 0; nt < 8; ++nt){ float d = vs[nt] - mean; sq += d*d; }
      sq += __shfl_xor(sq, 1); sq += __shfl_xor(sq, 2);
      sq += __shfl_xor(sq, 4); sq += __shfl_xor(sq, 8);
      float rs = rsqrtf(sq * (1.f/DD) + 1e-5f);
      #pragma unroll
      for (int nt = 0; nt < 8; ++nt){
        int col = nt*16 + l16;
        float o = (vs[nt] - mean)*rs*g[col] + beta[col];
        cur[(size_t)row*DD + col]  = o;
        curb[(size_t)row*DD + col] = f2bf(o);
      }
    }
  }
}

// ---------------- final masked mean, two-stage ----------------
__global__ __launch_bounds__(128) void reduce1_kernel(
    const float* __restrict__ cur, const float* __restrict__ mask,
    float* __restrict__ partial, float* __restrict__ cnt)
{
  int b = blockIdx.x, c = blockIdx.y, t = threadIdx.x;
  float acc = 0.f, cn = 0.f;
  for (int s = c*128; s < c*128 + 128; ++s){
    float mk = mask[b*NPER + s];
    acc += cur[(size_t)(b*NPER + s)*DD + t] * mk;
    cn += mk;
  }
  partial[(size_t)(b*8 + c)*DD + t] = acc;
  if (t == 0) cnt[b*8 + c] = cn;
}
__global__ __launch_bounds__(128) void reduce2_kernel(
    const float* __restrict__ partial, const float* __restrict__ cnt,
    const int* __restrict__ flag, void* __restrict__ out)
{
  int b = blockIdx.x, t = threadIdx.x;
  float acc = 0.f, cn = 0.f;
  #pragma unroll
  for (int c = 0; c < 8; ++c){
    acc += partial[(size_t)(b*8 + c)*DD + t];
    cn  += cnt[b*8 + c];
  }
  float val = acc / cn;
  if (*flag) ((u16*)out)[b*DD + t] = f2bf(val);
  else       ((float*)out)[b*DD + t] = val;
}

// ---------------- host ----------------
extern "C" void kernel_launch(void* const* d_in, const int* in_sizes, int n_in,
                              void* d_out, int out_size, void* d_ws, size_t ws_size,
                              hipStream_t stream)
{
  (void)in_sizes; (void)n_in; (void)out_size; (void)ws_size;
  char* ws = (char*)d_ws;
  int*   flag   = (int*)(ws + OFF_FLAG);
  int*   starts = (int*)(ws + OFF_STARTS);
  float* BIN  = (float*)(ws + OFF_BIN);
  float* BQKV = (float*)(ws + OFF_BQKV);
  float* BO   = (float*)(ws + OFF_BO);
  float* B1   = (float*)(ws + OFF_B1);
  float* B2   = (float*)(ws + OFF_B2);
  float* LN1G = (float*)(ws + OFF_LN1G);
  float* LN1B = (float*)(ws + OFF_LN1B);
  float* LN2G = (float*)(ws + OFF_LN2G);
  float* LN2B = (float*)(ws + OFF_LN2B);
  u16* XB    = (u16*)(ws + OFF_XB);
  u16* WINB  = (u16*)(ws + OFF_WINB);
  u16* WQKVB = (u16*)(ws + OFF_WQKVB);
  u16* WOB   = (u16*)(ws + OFF_WOB);
  u16* W1B   = (u16*)(ws + OFF_W1B);
  u16* W2B   = (u16*)(ws + OFF_W2B);
  float* CUR = (float*)(ws + OFF_CUR);
  float* TMP = (float*)(ws + OFF_TMP);
  u16* CURB  = (u16*)(ws + OFF_CURB);
  u16* QKVB  = (u16*)(ws + OFF_QKVB);
  u16* ATTNOB= (u16*)(ws + OFF_ATTNOB);
  float* MASK= (float*)(ws + OFF_MASK);
  u16* VT    = (u16*)(ws + OFF_VT);
  float* RED = (float*)(ws + OFF_RED);
  float* CNT = (float*)(ws + OFF_CNT);

  detect_kernel<<<1, 256, 0, stream>>>((const unsigned*)d_in[0], flag);
  starts_kernel<<<1, 64, 0, stream>>>((const int*)d_in[1], starts);

  ConvArgs ca;
  ca.s[0]  = { d_in[0],  XB,    NTOT*INDIM, 1 };
  ca.s[1]  = { d_in[2],  WINB,  DD*INDIM,   1 };
  ca.s[2]  = { d_in[4],  WQKVB, LL*3*DD*DD, 1 };
  ca.s[3]  = { d_in[6],  WOB,   LL*DD*DD,   1 };
  ca.s[4]  = { d_in[8],  W1B,   LL*DFF*DD,  1 };
  ca.s[5]  = { d_in[10], W2B,   LL*DD*DFF,  1 };
  ca.s[6]  = { d_in[3],  BIN,   DD,         0 };
  ca.s[7]  = { d_in[5],  BQKV,  LL*3*DD,    0 };
  ca.s[8]  = { d_in[7],  BO,    LL*DD,      0 };
  ca.s[9]  = { d_in[9],  B1,    LL*DFF,     0 };
  ca.s[10] = { d_in[11], B2,    LL*DD,      0 };
  ca.s[11] = { d_in[12], LN1G,  LL*DD,      0 };
  ca.s[12] = { d_in[13], LN1B,  LL*DD,      0 };
  ca.s[13] = { d_in[14], LN2G,  LL*DD,      0 };
  ca.s[14] = { d_in[15], LN2B,  LL*DD,      0 };
  int nblk = 0;
  for (int i = 0; i < 15; ++i) nblk += (ca.s[i].n + 1023) >> 10;
  convall_kernel<<<nblk, 256, 0, stream>>>(ca, flag);

  gemm_bf16<<<dim3(NTOT/64, DD/64), 256, 0, stream>>>(
      XB, INDIM, WINB, INDIM, BIN, TMP, nullptr, DD, INDIM, 0);
  scatter_kernel<<<NTOT, 128, 0, stream>>>(TMP, (const int*)d_in[1], starts, CUR, CURB, MASK);

  for (int l = 0; l < LL; ++l){
    wgemm_kernel<<<dim3(NTOT/64, 3), 256, 0, stream>>>(
        CURB, WQKVB + (size_t)l*3*DD*DD, BQKV + l*3*DD, 0,
        QKVB, 384, VT, nullptr, nullptr, nullptr, nullptr);
    fattn_kernel<<<dim3(NPER/64, HH, BB), 256, 0, stream>>>(QKVB, VT, ATTNOB);
    wgemm_kernel<<<dim3(NTOT/64, 1), 256, 0, stream>>>(
        ATTNOB, WOB + (size_t)l*DD*DD, BO + l*DD, 1,
        nullptr, 0, nullptr, CUR, CURB, LN1G + l*DD, LN1B + l*DD);
    ffn_kernel<<<dim3(NTOT/128), 256, 0, stream>>>(
        CURB, W1B + (size_t)l*DFF*DD, W2B + (size_t)l*DD*DFF,
        B1 + l*DFF, B2 + l*DD, LN2G + l*DD, LN2B + l*DD, CUR, CURB);
  }

  reduce1_kernel<<<dim3(BB, 8), 128, 0, stream>>>(CUR, MASK, RED, CNT);
  reduce2_kernel<<<BB, 128, 0, stream>>>(RED, CNT, flag, d_out);
}

// Round 9
// 526.255 us; speedup vs baseline: 1.1551x; 1.1551x over previous
//
#include <hip/hip_runtime.h>
#include <hip/hip_bf16.h>
#include <stdint.h>

// ---------------- static problem sizes ----------------
#define BB    32
#define NPER  1024
#define NTOT  32768
#define DD    128
#define HH    4
#define HD    32
#define LL    3
#define DFF   2048
#define INDIM 64
#define QKSCALE 0.17677669529663687f

typedef unsigned short u16;
typedef short bf16x8 __attribute__((ext_vector_type(8)));   // 8 bf16 (4 VGPRs)
typedef float f32x4 __attribute__((ext_vector_type(4)));
typedef float f32x16 __attribute__((ext_vector_type(16)));  // 32x32 MFMA acc

// address-space casts for global_load_lds (direct global->LDS DMA)
#define AS_GLOBAL(p) ((const __attribute__((address_space(1))) void*)(p))
#define AS_LDS(p)    ((__attribute__((address_space(3))) void*)(p))

__device__ __forceinline__ float bf2f(u16 v){
  unsigned u = ((unsigned)v) << 16; float f; __builtin_memcpy(&f, &u, 4); return f;
}
__device__ __forceinline__ u16 f2bf(float f){
  unsigned u; __builtin_memcpy(&u, &f, 4);
  unsigned lsb = (u >> 16) & 1u;
  u += 0x7fffu + lsb;              // round-to-nearest-even
  return (u16)(u >> 16);
}

// ---------------- workspace layout (bytes) ----------------
constexpr size_t OFF_FLAG   = 0;
constexpr size_t OFF_STARTS = 256;
constexpr size_t OFF_BIN    = 1024;
constexpr size_t OFF_BQKV   = OFF_BIN   + 128*4;
constexpr size_t OFF_BO     = OFF_BQKV  + 1152*4;
constexpr size_t OFF_B1     = OFF_BO    + 384*4;
constexpr size_t OFF_B2     = OFF_B1    + 6144*4;
constexpr size_t OFF_LN1G   = OFF_B2    + 384*4;
constexpr size_t OFF_LN1B   = OFF_LN1G  + 384*4;
constexpr size_t OFF_LN2G   = OFF_LN1B  + 384*4;
constexpr size_t OFF_LN2B   = OFF_LN2G  + 384*4;
constexpr size_t OFF_XB     = 40960;
constexpr size_t OFF_WINB   = OFF_XB    + (size_t)2097152*2;
constexpr size_t OFF_WQKVB  = OFF_WINB  + (size_t)8192*2;
constexpr size_t OFF_WOB    = OFF_WQKVB + (size_t)147456*2;
constexpr size_t OFF_W1B    = OFF_WOB   + (size_t)49152*2;
constexpr size_t OFF_W2B    = OFF_W1B   + (size_t)786432*2;
constexpr size_t OFF_CUR    = OFF_W2B   + (size_t)786432*2;
constexpr size_t OFF_TMP    = OFF_CUR   + (size_t)4194304*4;
constexpr size_t OFF_CURB   = OFF_TMP   + (size_t)4194304*4;
constexpr size_t OFF_QKVB   = OFF_CURB  + (size_t)4194304*2;
constexpr size_t OFF_ATTNOB = OFF_QKVB  + (size_t)12582912*2;
constexpr size_t OFF_ACTB   = OFF_ATTNOB+ (size_t)4194304*2;     // (unused now)
constexpr size_t OFF_MASK   = OFF_ACTB  + (size_t)16777216*2;
constexpr size_t OFF_VT     = OFF_MASK  + (size_t)NTOT*4;
constexpr size_t OFF_RED    = OFF_VT    + (size_t)4096*1024*2;
constexpr size_t OFF_CNT    = OFF_RED   + (size_t)32*8*128*4;

// ---------------- dtype detection ----------------
__device__ __forceinline__ int plaus(unsigned bits){
  if ((bits << 1) == 0u) return 1;
  unsigned e = (bits >> 23) & 0xFFu;
  return (e >= 100u && e <= 140u) ? 1 : 0;
}
__global__ void detect_kernel(const unsigned* __restrict__ x, int* __restrict__ flag){
  __shared__ int red[256];
  int t = threadIdx.x, c = 0;
  for (int i = t; i < 2048; i += 256){
    unsigned w = x[i];
    c += (plaus(w << 16) & plaus(w & 0xFFFF0000u));
  }
  red[t] = c; __syncthreads();
  for (int s = 128; s > 0; s >>= 1){ if (t < s) red[t] += red[t+s]; __syncthreads(); }
  if (t == 0) *flag = (red[0] >= 1229) ? 1 : 0;
}

__global__ void starts_kernel(const int* __restrict__ batch, int* __restrict__ starts){
  int b = threadIdx.x;
  if (b < BB){
    int lo = 0, hi = NTOT;
    while (lo < hi){ int mid = (lo + hi) >> 1; if (batch[mid] < b) lo = mid + 1; else hi = mid; }
    starts[b] = lo;
  }
}

// ---------------- fused conversion of all 15 float tensors (1 launch) ----------------
struct ConvSeg { const void* src; void* dst; int n; int tobf; };
struct ConvArgs { ConvSeg s[15]; };

__global__ __launch_bounds__(256) void convall_kernel(ConvArgs a, const int* __restrict__ flag){
  const int isb = *flag;
  const int blk = blockIdx.x;
  int seg = -1, base = 0, lb = 0;
  #pragma unroll
  for (int i = 0; i < 15; ++i){
    int nb = (a.s[i].n + 1023) >> 10;
    if (seg < 0){
      if (blk < base + nb){ seg = i; lb = blk - base; }
      base += nb;
    }
  }
  const ConvSeg sg = a.s[seg];
  const int idx = lb*1024 + threadIdx.x*4;
  if (idx >= sg.n) return;
  if (sg.tobf){
    u16* dst = (u16*)sg.dst + idx;
    if (isb){
      *(uint2*)dst = *(const uint2*)((const u16*)sg.src + idx);
    } else {
      const float* s4 = (const float*)sg.src + idx;
      dst[0] = f2bf(s4[0]); dst[1] = f2bf(s4[1]);
      dst[2] = f2bf(s4[2]); dst[3] = f2bf(s4[3]);
    }
  } else {
    float* dst = (float*)sg.dst + idx;
    if (isb){
      const u16* s4 = (const u16*)sg.src + idx;
      dst[0] = bf2f(s4[0]); dst[1] = bf2f(s4[1]);
      dst[2] = bf2f(s4[2]); dst[3] = bf2f(s4[3]);
    } else {
      *(float4*)dst = *(const float4*)((const float*)sg.src + idx);
    }
  }
}

// ---------------- legacy small GEMM (input projection only) ----------------
__global__ __launch_bounds__(256) void gemm_bf16(
    const u16* __restrict__ A, int lda,
    const u16* __restrict__ W, int ldw,
    const float* __restrict__ bias,
    float* __restrict__ Cf, u16* __restrict__ Cb,
    int N, int K, int flags)
{
  __shared__ __align__(16) u16 At[64][32];
  __shared__ __align__(16) u16 Wt[64][32];
  const int t = threadIdx.x;
  const int m0 = blockIdx.x * 64, n0 = blockIdx.y * 64;
  const int wave = t >> 6, lane = t & 63;
  const int quad = lane >> 4, l16 = lane & 15;
  const int lr = t >> 2, lc = (t & 3) * 8;

  f32x4 acc[4];
  #pragma unroll
  for (int i = 0; i < 4; ++i){ acc[i][0]=0.f; acc[i][1]=0.f; acc[i][2]=0.f; acc[i][3]=0.f; }

  const u16* Arow = A + (size_t)(m0 + lr) * lda + lc;
  const u16* Wrow = W + (size_t)(n0 + lr) * ldw + lc;

  for (int k0 = 0; k0 < K; k0 += 32){
    uint4 av = *(const uint4*)(Arow + k0);
    uint4 wv = *(const uint4*)(Wrow + k0);
    __syncthreads();
    *(uint4*)&At[lr][lc] = av;
    *(uint4*)&Wt[lr][lc] = wv;
    __syncthreads();
    bf16x8 af = *(const bf16x8*)&At[wave*16 + l16][quad*8];
    #pragma unroll
    for (int nt = 0; nt < 4; ++nt){
      bf16x8 wf = *(const bf16x8*)&Wt[nt*16 + l16][quad*8];
      acc[nt] = __builtin_amdgcn_mfma_f32_16x16x32_bf16(af, wf, acc[nt], 0, 0, 0);
    }
  }
  const int row = m0 + wave*16 + quad*4;
  #pragma unroll
  for (int nt = 0; nt < 4; ++nt){
    const int col = n0 + nt*16 + l16;
    const float bv = bias ? bias[col] : 0.f;
    #pragma unroll
    for (int r = 0; r < 4; ++r){
      size_t idx = (size_t)(row + r) * N + col;
      float v = acc[nt][r] + bv;
      if (flags & 1) v = fmaxf(v, 0.f);
      if (Cf) Cf[idx] = v;
      if (Cb) Cb[idx] = f2bf(v);
    }
  }
}

// ---------------- scatter projected nodes into padded layout + mask ----------------
__global__ __launch_bounds__(128) void scatter_kernel(
    const float* __restrict__ hlin, const int* __restrict__ batch,
    const int* __restrict__ starts, float* __restrict__ cur,
    u16* __restrict__ curb, float* __restrict__ mask)
{
  int i = blockIdx.x, t = threadIdx.x;
  int g = batch[i];
  int p = i - starts[g];
  float v = hlin[(size_t)i*DD + t];
  float s = v;
  #pragma unroll
  for (int off = 32; off; off >>= 1) s += __shfl_xor(s, off);
  __shared__ float sh[2];
  if ((t & 63) == 0) sh[t >> 6] = s;
  __syncthreads();
  float rowsum = sh[0] + sh[1];
  if ((unsigned)p < (unsigned)NPER && (unsigned)g < (unsigned)BB){
    size_t j = (size_t)g*NPER + p;
    cur[j*DD + t]  = v;
    curb[j*DD + t] = f2bf(v);
    if (t == 0) mask[j] = (rowsum != 0.f) ? 1.f : 0.f;
  }
}

// ---------------- MFMA flash attention v2 ----------------
__global__ __launch_bounds__(256) void fattn_kernel(
    const u16* __restrict__ qkvb,   // [NTOT][384]
    const u16* __restrict__ vt,     // [B*H*HD][NPER]
    u16* __restrict__ attnob)       // [NTOT][128]
{
  __shared__ __align__(16) u16 Klds[2][2048];      // [c(4)][r(64)][8]
  __shared__ __align__(16) u16 Vl[2][2048];        // [cv(8)][d(32)][8]
  __shared__ __align__(16) u16 Pl[4][16*72];       // per-wave P [q][s], pitch 72

  const int t = threadIdx.x;
  const int wave = t >> 6, lane = t & 63;
  const int quad = lane >> 4, l16 = lane & 15;
  const int q0 = blockIdx.x * 64;
  const int h = blockIdx.y, b = blockIdx.z;
  const size_t qkvbase = (size_t)b * NPER * 384;
  const u16* Kg = qkvb + qkvbase + 128 + h*HD;
  const u16* Vg = vt + (size_t)((b*HH + h)*HD) * NPER;

  bf16x8 qf;
  {
    const u16* qp = qkvb + qkvbase + (size_t)(q0 + wave*16 + l16)*384 + h*HD + quad*8;
    uint4 qv = *(const uint4*)qp;
    u16 raw[8]; __builtin_memcpy(raw, &qv, 16);
    #pragma unroll
    for (int j = 0; j < 8; ++j) qf[j] = (short)f2bf(bf2f(raw[j]) * QKSCALE);
  }

  const int vcv = wave*2 + (lane >> 5), vd = lane & 31;
  auto stage = [&](int buf, int kt){
    __builtin_amdgcn_global_load_lds(
        AS_GLOBAL(Kg + (size_t)(kt*64 + lane)*384 + wave*8),
        AS_LDS(&Klds[buf][wave*64*8]), 16, 0, 0);
    __builtin_amdgcn_global_load_lds(
        AS_GLOBAL(Vg + (size_t)vd*NPER + kt*64 + vcv*8),
        AS_LDS(&Vl[buf][wave*64*8]), 16, 0, 0);
  };

  float lsum = 0.f;
  f32x4 o0 = {0.f,0.f,0.f,0.f}, o1 = {0.f,0.f,0.f,0.f};
  u16* Pw = &Pl[wave][0];

  stage(0, 0);
  asm volatile("s_waitcnt vmcnt(0)" ::: "memory");
  __syncthreads();

  for (int kt = 0; kt < 16; ++kt){
    const int buf = kt & 1;
    if (kt + 1 < 16) stage(buf ^ 1, kt + 1);

    f32x4 sfr[4];
    #pragma unroll
    for (int nt = 0; nt < 4; ++nt){
      bf16x8 kf = *(const bf16x8*)&Klds[buf][(quad*64 + nt*16 + l16)*8];
      f32x4 z = {0.f,0.f,0.f,0.f};
      sfr[nt] = __builtin_amdgcn_mfma_f32_16x16x32_bf16(kf, qf, z, 0, 0, 0);
    }

    float ps = 0.f;
    #pragma unroll
    for (int nt = 0; nt < 4; ++nt){
      float e0 = __expf(sfr[nt][0]), e1 = __expf(sfr[nt][1]);
      float e2 = __expf(sfr[nt][2]), e3 = __expf(sfr[nt][3]);
      ps += (e0 + e1) + (e2 + e3);
      uint2 w;
      w.x = (unsigned)f2bf(e0) | ((unsigned)f2bf(e1) << 16);
      w.y = (unsigned)f2bf(e2) | ((unsigned)f2bf(e3) << 16);
      *(uint2*)&Pw[l16*72 + nt*16 + quad*4] = w;
    }
    ps += __shfl_xor(ps, 16);
    ps += __shfl_xor(ps, 32);
    lsum += ps;
    asm volatile("s_waitcnt lgkmcnt(0)" ::: "memory");

    #pragma unroll
    for (int kk = 0; kk < 2; ++kk){
      bf16x8 pf = *(const bf16x8*)&Pw[l16*72 + kk*32 + quad*8];
      bf16x8 v0 = *(const bf16x8*)&Vl[buf][((kk*4 + quad)*32 + l16)*8];
      bf16x8 v1 = *(const bf16x8*)&Vl[buf][((kk*4 + quad)*32 + 16 + l16)*8];
      o0 = __builtin_amdgcn_mfma_f32_16x16x32_bf16(pf, v0, o0, 0, 0, 0);
      o1 = __builtin_amdgcn_mfma_f32_16x16x32_bf16(pf, v1, o1, 0, 0, 0);
    }

    if (kt + 1 < 16){
      asm volatile("s_waitcnt vmcnt(0)" ::: "memory");
      __syncthreads();
    }
  }

  #pragma unroll
  for (int r = 0; r < 4; ++r){
    float inv = 1.f / __shfl(lsum, quad*4 + r);
    int row = q0 + wave*16 + quad*4 + r;
    size_t base = (size_t)(b*NPER + row)*DD + h*HD;
    attnob[base + l16]      = f2bf(o0[r] * inv);
    attnob[base + 16 + l16] = f2bf(o1[r] * inv);
  }
}

// ---------------- LN epilogue (wave owns 16 rows): out = LN(resid + O + bias) ----------------
__device__ __forceinline__ void epilogue_ln64(
    const f32x4 O[8], int m0, int wave, int quad, int l16,
    const float* __restrict__ bias, const float* __restrict__ g,
    const float* __restrict__ beta, float* __restrict__ cur,
    u16* __restrict__ curb)
{
  #pragma unroll
  for (int rr = 0; rr < 4; ++rr){
    int row = m0 + wave*16 + quad*4 + rr;
    float vs[8], sum = 0.f;
    #pragma unroll
    for (int nt = 0; nt < 8; ++nt){
      int col = nt*16 + l16;
      float v = O[nt][rr] + bias[col] + cur[(size_t)row*DD + col];
      vs[nt] = v; sum += v;
    }
    sum += __shfl_xor(sum, 1); sum += __shfl_xor(sum, 2);
    sum += __shfl_xor(sum, 4); sum += __shfl_xor(sum, 8);
    float mean = sum * (1.f/DD);
    float sq = 0.f;
    #pragma unroll
    for (int nt = 0; nt < 8; ++nt){ float d = vs[nt] - mean; sq += d*d; }
    sq += __shfl_xor(sq, 1); sq += __shfl_xor(sq, 2);
    sq += __shfl_xor(sq, 4); sq += __shfl_xor(sq, 8);
    float rs = rsqrtf(sq * (1.f/DD) + 1e-5f);
    #pragma unroll
    for (int nt = 0; nt < 8; ++nt){
      int col = nt*16 + l16;
      float o = (vs[nt] - mean)*rs*g[col] + beta[col];
      cur[(size_t)row*DD + col]  = o;
      curb[(size_t)row*DD + col] = f2bf(o);
    }
  }
}

// ---------------- 64-row-block GEMM, W (128x128 slice) in LDS, A-frags in regs ----------------
__global__ __launch_bounds__(256) void wgemm_kernel(
    const u16* __restrict__ A,        // [M][128] bf16
    const u16* __restrict__ Wbase,    // [gridDim.y*128][128] bf16
    const float* __restrict__ biasb,  // [gridDim.y*128]
    int mode,
    u16* __restrict__ outb, int opitch,
    u16* __restrict__ vtout,
    float* __restrict__ cur, u16* __restrict__ curb,
    const float* __restrict__ g, const float* __restrict__ beta)
{
  __shared__ __align__(16) u16 Wl[16384];          // 128x128, XOR-swizzled chunks
  const int t = threadIdx.x, wave = t >> 6, lane = t & 63;
  const int quad = lane >> 4, l16 = lane & 15;
  const int m0 = blockIdx.x * 64, nb = blockIdx.y;
  const u16* Wsl = Wbase + (size_t)nb * 16384;
  const float* bias = biasb + nb * 128;

  #pragma unroll
  for (int j = 0; j < 8; ++j){
    int s = t + 256*j;
    int r = s >> 4, cx = (s & 15) ^ (r & 15);
    *(uint4*)&Wl[s*8] = *(const uint4*)(Wsl + (size_t)r*128 + cx*8);
  }
  bf16x8 af[4];
  #pragma unroll
  for (int kk = 0; kk < 4; ++kk)
    af[kk] = *(const bf16x8*)(A + (size_t)(m0 + wave*16 + l16)*128 + kk*32 + quad*8);
  __syncthreads();

  f32x4 O[8];
  #pragma unroll
  for (int nt = 0; nt < 8; ++nt){ O[nt][0]=0.f; O[nt][1]=0.f; O[nt][2]=0.f; O[nt][3]=0.f; }

  #pragma unroll
  for (int nt = 0; nt < 8; ++nt){
    int row = nt*16 + l16;
    bf16x8 wf[4];
    #pragma unroll
    for (int kk = 0; kk < 4; ++kk)
      wf[kk] = *(const bf16x8*)&Wl[(row*16 + ((kk*4 + quad) ^ l16))*8];
    #pragma unroll
    for (int kk = 0; kk < 4; ++kk)
      O[nt] = __builtin_amdgcn_mfma_f32_16x16x32_bf16(af[kk], wf[kk], O[nt], 0, 0, 0);
  }

  if (mode == 0){
    if (nb == 2 && vtout){
      int rowb = m0 + wave*16 + quad*4;
      int bg = rowb >> 10, s = rowb & 1023;
      #pragma unroll
      for (int nt = 0; nt < 8; ++nt){
        int col = nt*16 + l16;
        int hh = col >> 5, d = col & 31;
        float v0 = O[nt][0] + bias[col], v1 = O[nt][1] + bias[col];
        float v2 = O[nt][2] + bias[col], v3 = O[nt][3] + bias[col];
        uint2 w;
        w.x = (unsigned)f2bf(v0) | ((unsigned)f2bf(v1) << 16);
        w.y = (unsigned)f2bf(v2) | ((unsigned)f2bf(v3) << 16);
        *(uint2*)(vtout + (size_t)((bg*HH + hh)*HD + d)*NPER + s) = w;
      }
    } else {
      #pragma unroll
      for (int rr = 0; rr < 4; ++rr){
        int row = m0 + wave*16 + quad*4 + rr;
        #pragma unroll
        for (int nt = 0; nt < 8; ++nt){
          int col = nt*16 + l16;
          outb[(size_t)row*opitch + nb*128 + col] = f2bf(O[nt][rr] + bias[col]);
        }
      }
    }
  } else {
    epilogue_ln64(O, m0, wave, quad, l16, bias, g, beta, cur, curb);
  }
}

// ---------------- fused FFN v4: 64-row blocks, 32x32x16 MFMA, wave-pairs ----------------
// 512 blocks (2 blocks/CU, 8 waves/CU). Wave pair (2 waves) shares 32 act rows:
// phase1: each wave computes its dff-half C[dff32][act32] (operand-swapped,
// 2 accumulator chains), packs P (bf16) into pair-shared [32][72] buffer;
// phase2: each wave computes its 64-col half of O[32][128] with full K=64.
// 32x32x16 gives 2x FLOP per LDS b128 frag read vs 16x16x32 (R7 was LDS-bound).
// Mid-chunk barrier uses raw s_barrier + lgkmcnt-only drain so in-flight W DMA
// (global_load_lds) is not serialized by the compiler's vmcnt(0) auto-drain.
__global__ __launch_bounds__(256, 2) void ffn_kernel(
    const u16* __restrict__ Ag,       // CURB [M][128]
    const u16* __restrict__ W1g,      // [2048][128]
    const u16* __restrict__ W2g,      // [128][2048]
    const float* __restrict__ b1,
    const float* __restrict__ b2,
    const float* __restrict__ g, const float* __restrict__ beta,
    float* __restrict__ cur, u16* __restrict__ curb)
{
  __shared__ __align__(16) u16 W1l[2][8192];       // 64x128 chunk, swizzled, x2 buf
  __shared__ __align__(16) u16 W2l[2][8192];       // 128x64 chunk, swizzled, x2 buf
  __shared__ __align__(16) u16 Pl[2][32*72];       // per-pair P[act32][dff64], pitch 72
  __shared__ float exs[2][2][32];                  // LN partial row-sums
  __shared__ float exq[2][2][32];                  // LN partial row-sq

  const int t = threadIdx.x, wave = t >> 6, lane = t & 63;
  const int pair = wave >> 1, q = wave & 1;
  const int a32 = lane & 31, h = lane >> 5;
  const int m0 = blockIdx.x * 64;
  u16* Pp = &Pl[pair][0];

  auto stage = [&](int buf, int dffc){
    #pragma unroll
    for (int i = 0; i < 4; ++i){
      const int s0 = wave*256 + i*64;
      const int s  = s0 + lane;
      { int r = s >> 4, cx = (s & 15) ^ (r & 15);
        __builtin_amdgcn_global_load_lds(
            AS_GLOBAL(W1g + (size_t)(dffc + r)*128 + cx*8),
            AS_LDS(&W1l[buf][s0*8]), 16, 0, 0); }
      { int r = s >> 3, cx = (s & 7) ^ (r & 7);
        __builtin_amdgcn_global_load_lds(
            AS_GLOBAL(W2g + (size_t)r*DFF + dffc + cx*8),
            AS_LDS(&W2l[buf][s0*8]), 16, 0, 0); }
    }
  };

  // act B-frags: B[n=act=a32][k=kk*16+h*8+j]; pair shares rows m0+pair*32..+31
  bf16x8 af[8];
  #pragma unroll
  for (int kk = 0; kk < 8; ++kk)
    af[kk] = *(const bf16x8*)(Ag + (size_t)(m0 + pair*32 + a32)*128 + kk*16 + h*8);

  f32x16 O[2] = {{0.f}, {0.f}};
  #pragma unroll
  for (int nt = 0; nt < 2; ++nt)
    #pragma unroll
    for (int j = 0; j < 16; ++j) O[nt][j] = 0.f;

  stage(0, 0);
  asm volatile("s_waitcnt vmcnt(0)" ::: "memory");
  __syncthreads();

  const int w1row = q*32 + a32;                    // this wave's dff-half rows
  for (int c = 0; c < 32; ++c){
    const int buf = c & 1;
    const int dffc = c*64;
    if (c + 1 < 32) stage(buf ^ 1, (c + 1)*64);

    // ---- phase 1: C[dff32][act32] = W1half @ A^T, two accumulator chains ----
    f32x16 s0, s1;
    #pragma unroll
    for (int j = 0; j < 16; ++j){ s0[j] = 0.f; s1[j] = 0.f; }
    #pragma unroll
    for (int kk = 0; kk < 8; kk += 2){
      bf16x8 wfa = *(const bf16x8*)&W1l[buf][(w1row*16 + (((kk  )*2 + h) ^ (w1row & 15)))*8];
      bf16x8 wfb = *(const bf16x8*)&W1l[buf][(w1row*16 + (((kk+1)*2 + h) ^ (w1row & 15)))*8];
      s0 = __builtin_amdgcn_mfma_f32_32x32x16_bf16(wfa, af[kk],   s0, 0, 0, 0);
      s1 = __builtin_amdgcn_mfma_f32_32x32x16_bf16(wfb, af[kk+1], s1, 0, 0, 0);
    }
    // bias + relu + pack: C row(dff_local) = (reg&3) + 8*(reg>>2) + 4*h
    #pragma unroll
    for (int gi = 0; gi < 4; ++gi){
      int dffl = q*32 + gi*8 + h*4;
      f32x4 b1v = *(const f32x4*)&b1[dffc + dffl];
      float v0 = fmaxf(s0[gi*4+0] + s1[gi*4+0] + b1v[0], 0.f);
      float v1 = fmaxf(s0[gi*4+1] + s1[gi*4+1] + b1v[1], 0.f);
      float v2 = fmaxf(s0[gi*4+2] + s1[gi*4+2] + b1v[2], 0.f);
      float v3 = fmaxf(s0[gi*4+3] + s1[gi*4+3] + b1v[3], 0.f);
      uint2 w;
      w.x = (unsigned)f2bf(v0) | ((unsigned)f2bf(v1) << 16);
      w.y = (unsigned)f2bf(v2) | ((unsigned)f2bf(v3) << 16);
      *(uint2*)&Pp[a32*72 + dffl] = w;
    }
    // pair-shared P: LDS writes visible, but do NOT drain vmcnt (W DMA in flight)
    asm volatile("s_waitcnt lgkmcnt(0)\ns_barrier" ::: "memory");

    // ---- phase 2: O[act32][64-col half] += P @ W2c^T, K=64 ----
    bf16x8 pf[4];
    #pragma unroll
    for (int kk = 0; kk < 4; ++kk)
      pf[kk] = *(const bf16x8*)&Pp[a32*72 + kk*16 + h*8];
    #pragma unroll
    for (int nt = 0; nt < 2; ++nt){
      const int w2row = q*64 + nt*32 + a32;
      f32x16 acc = O[nt];
      #pragma unroll
      for (int kk = 0; kk < 4; ++kk){
        bf16x8 wf = *(const bf16x8*)&W2l[buf][(w2row*8 + ((kk*2 + h) ^ (w2row & 7)))*8];
        acc = __builtin_amdgcn_mfma_f32_32x32x16_bf16(pf[kk], wf, acc, 0, 0, 0);
      }
      O[nt] = acc;
    }

    // end of chunk: DMA for c+1 arrived + all P/W reads done before overwrite
    if (c + 1 < 32){
      asm volatile("s_waitcnt vmcnt(0) lgkmcnt(0)\ns_barrier" ::: "memory");
    }
  }

  // ---- epilogue: residual + LN2; cols split across wave pair ----
  const int col0 = q*64 + a32, col1 = q*64 + 32 + a32;
  const float g0 = g[col0], g1 = g[col1];
  const float be0 = beta[col0], be1 = beta[col1];
  const float bb0 = b2[col0], bb1 = b2[col1];

  float vs0[16], vs1[16], srow[16];
  #pragma unroll
  for (int reg = 0; reg < 16; ++reg){
    int rowl = (reg & 3) + 8*(reg >> 2) + 4*h;
    size_t rb = (size_t)(m0 + pair*32 + rowl) * DD;
    vs0[reg] = O[0][reg] + bb0 + cur[rb + col0];
    vs1[reg] = O[1][reg] + bb1 + cur[rb + col1];
    float s = vs0[reg] + vs1[reg];
    s += __shfl_xor(s, 1); s += __shfl_xor(s, 2);
    s += __shfl_xor(s, 4); s += __shfl_xor(s, 8); s += __shfl_xor(s, 16);
    srow[reg] = s;
  }
  __syncthreads();            // loop's last-chunk LDS reads done everywhere
  if (a32 == 0){
    #pragma unroll
    for (int reg = 0; reg < 16; ++reg)
      exs[pair][q][(reg & 3) + 8*(reg >> 2) + 4*h] = srow[reg];
  }
  __syncthreads();
  float mean[16];
  #pragma unroll
  for (int reg = 0; reg < 16; ++reg)
    mean[reg] = (srow[reg] + exs[pair][q ^ 1][(reg & 3) + 8*(reg >> 2) + 4*h]) * (1.f/DD);

  float qrow[16];
  #pragma unroll
  for (int reg = 0; reg < 16; ++reg){
    float d0 = vs0[reg] - mean[reg], d1 = vs1[reg] - mean[reg];
    float s = d0*d0 + d1*d1;
    s += __shfl_xor(s, 1); s += __shfl_xor(s, 2);
    s += __shfl_xor(s, 4); s += __shfl_xor(s, 8); s += __shfl_xor(s, 16);
    qrow[reg] = s;
  }
  if (a32 == 0){
    #pragma unroll
    for (int reg = 0; reg < 16; ++reg)
      exq[pair][q][(reg & 3) + 8*(reg >> 2) + 4*h] = qrow[reg];
  }
  __syncthreads();
  #pragma unroll
  for (int reg = 0; reg < 16; ++reg){
    int rowl = (reg & 3) + 8*(reg >> 2) + 4*h;
    float var = (qrow[reg] + exq[pair][q ^ 1][rowl]) * (1.f/DD);
    float rs = rsqrtf(var + 1e-5f);
    size_t rb = (size_t)(m0 + pair*32 + rowl) * DD;
    float o0 = (vs0[reg] - mean[reg])*rs*g0 + be0;
    float o1 = (vs1[reg] - mean[reg])*rs*g1 + be1;
    cur[rb + col0]  = o0;
    cur[rb + col1]  = o1;
    curb[rb + col0] = f2bf(o0);
    curb[rb + col1] = f2bf(o1);
  }
}

// ---------------- final masked mean, two-stage ----------------
__global__ __launch_bounds__(128) void reduce1_kernel(
    const float* __restrict__ cur, const float* __restrict__ mask,
    float* __restrict__ partial, float* __restrict__ cnt)
{
  int b = blockIdx.x, c = blockIdx.y, t = threadIdx.x;
  float acc = 0.f, cn = 0.f;
  for (int s = c*128; s < c*128 + 128; ++s){
    float mk = mask[b*NPER + s];
    acc += cur[(size_t)(b*NPER + s)*DD + t] * mk;
    cn += mk;
  }
  partial[(size_t)(b*8 + c)*DD + t] = acc;
  if (t == 0) cnt[b*8 + c] = cn;
}
__global__ __launch_bounds__(128) void reduce2_kernel(
    const float* __restrict__ partial, const float* __restrict__ cnt,
    const int* __restrict__ flag, void* __restrict__ out)
{
  int b = blockIdx.x, t = threadIdx.x;
  float acc = 0.f, cn = 0.f;
  #pragma unroll
  for (int c = 0; c < 8; ++c){
    acc += partial[(size_t)(b*8 + c)*DD + t];
    cn  += cnt[b*8 + c];
  }
  float val = acc / cn;
  if (*flag) ((u16*)out)[b*DD + t] = f2bf(val);
  else       ((float*)out)[b*DD + t] = val;
}

// ---------------- host ----------------
extern "C" void kernel_launch(void* const* d_in, const int* in_sizes, int n_in,
                              void* d_out, int out_size, void* d_ws, size_t ws_size,
                              hipStream_t stream)
{
  (void)in_sizes; (void)n_in; (void)out_size; (void)ws_size;
  char* ws = (char*)d_ws;
  int*   flag   = (int*)(ws + OFF_FLAG);
  int*   starts = (int*)(ws + OFF_STARTS);
  float* BIN  = (float*)(ws + OFF_BIN);
  float* BQKV = (float*)(ws + OFF_BQKV);
  float* BO   = (float*)(ws + OFF_BO);
  float* B1   = (float*)(ws + OFF_B1);
  float* B2   = (float*)(ws + OFF_B2);
  float* LN1G = (float*)(ws + OFF_LN1G);
  float* LN1B = (float*)(ws + OFF_LN1B);
  float* LN2G = (float*)(ws + OFF_LN2G);
  float* LN2B = (float*)(ws + OFF_LN2B);
  u16* XB    = (u16*)(ws + OFF_XB);
  u16* WINB  = (u16*)(ws + OFF_WINB);
  u16* WQKVB = (u16*)(ws + OFF_WQKVB);
  u16* WOB   = (u16*)(ws + OFF_WOB);
  u16* W1B   = (u16*)(ws + OFF_W1B);
  u16* W2B   = (u16*)(ws + OFF_W2B);
  float* CUR = (float*)(ws + OFF_CUR);
  float* TMP = (float*)(ws + OFF_TMP);
  u16* CURB  = (u16*)(ws + OFF_CURB);
  u16* QKVB  = (u16*)(ws + OFF_QKVB);
  u16* ATTNOB= (u16*)(ws + OFF_ATTNOB);
  float* MASK= (float*)(ws + OFF_MASK);
  u16* VT    = (u16*)(ws + OFF_VT);
  float* RED = (float*)(ws + OFF_RED);
  float* CNT = (float*)(ws + OFF_CNT);

  detect_kernel<<<1, 256, 0, stream>>>((const unsigned*)d_in[0], flag);
  starts_kernel<<<1, 64, 0, stream>>>((const int*)d_in[1], starts);

  ConvArgs ca;
  ca.s[0]  = { d_in[0],  XB,    NTOT*INDIM, 1 };
  ca.s[1]  = { d_in[2],  WINB,  DD*INDIM,   1 };
  ca.s[2]  = { d_in[4],  WQKVB, LL*3*DD*DD, 1 };
  ca.s[3]  = { d_in[6],  WOB,   LL*DD*DD,   1 };
  ca.s[4]  = { d_in[8],  W1B,   LL*DFF*DD,  1 };
  ca.s[5]  = { d_in[10], W2B,   LL*DD*DFF,  1 };
  ca.s[6]  = { d_in[3],  BIN,   DD,         0 };
  ca.s[7]  = { d_in[5],  BQKV,  LL*3*DD,    0 };
  ca.s[8]  = { d_in[7],  BO,    LL*DD,      0 };
  ca.s[9]  = { d_in[9],  B1,    LL*DFF,     0 };
  ca.s[10] = { d_in[11], B2,    LL*DD,      0 };
  ca.s[11] = { d_in[12], LN1G,  LL*DD,      0 };
  ca.s[12] = { d_in[13], LN1B,  LL*DD,      0 };
  ca.s[13] = { d_in[14], LN2G,  LL*DD,      0 };
  ca.s[14] = { d_in[15], LN2B,  LL*DD,      0 };
  int nblk = 0;
  for (int i = 0; i < 15; ++i) nblk += (ca.s[i].n + 1023) >> 10;
  convall_kernel<<<nblk, 256, 0, stream>>>(ca, flag);

  gemm_bf16<<<dim3(NTOT/64, DD/64), 256, 0, stream>>>(
      XB, INDIM, WINB, INDIM, BIN, TMP, nullptr, DD, INDIM, 0);
  scatter_kernel<<<NTOT, 128, 0, stream>>>(TMP, (const int*)d_in[1], starts, CUR, CURB, MASK);

  for (int l = 0; l < LL; ++l){
    wgemm_kernel<<<dim3(NTOT/64, 3), 256, 0, stream>>>(
        CURB, WQKVB + (size_t)l*3*DD*DD, BQKV + l*3*DD, 0,
        QKVB, 384, VT, nullptr, nullptr, nullptr, nullptr);
    fattn_kernel<<<dim3(NPER/64, HH, BB), 256, 0, stream>>>(QKVB, VT, ATTNOB);
    wgemm_kernel<<<dim3(NTOT/64, 1), 256, 0, stream>>>(
        ATTNOB, WOB + (size_t)l*DD*DD, BO + l*DD, 1,
        nullptr, 0, nullptr, CUR, CURB, LN1G + l*DD, LN1B + l*DD);
    ffn_kernel<<<dim3(NTOT/64), 256, 0, stream>>>(
        CURB, W1B + (size_t)l*DFF*DD, W2B + (size_t)l*DD*DFF,
        B1 + l*DFF, B2 + l*DD, LN2G + l*DD, LN2B + l*DD, CUR, CURB);
  }

  reduce1_kernel<<<dim3(BB, 8), 128, 0, stream>>>(CUR, MASK, RED, CNT);
  reduce2_kernel<<<BB, 128, 0, stream>>>(RED, CNT, flag, d_out);
}